// Round 1
// 1080.369 us; speedup vs baseline: 1.1489x; 1.1489x over previous
//
#include <hip/hip_runtime.h>
#include <cmath>

#define DF 3200
#define NB 32
#define NN 100

// ws layout (float offsets)
#define OFF_ALPHA 0
#define OFF_GATES 128                     // [b*4 + {0,1,2}]
#define OFF_HS    256                     // [b][3200]
#define OFF_CB    (OFF_HS + NB*DF)        // [i][b][4]  cheb features
#define OFF_PW    (OFF_CB + NB*DF*4)      // [i][b][4]  taylor powers (pad 0)
#define OFF_SILU  (OFF_PW + NB*DF*4)      // [i][b]
#define OFF_SB    (OFF_SILU + NB*DF)      // [i][b][8]  spline bases

// async global->LDS, 16B per lane (dest = wave-uniform base + lane*16)
__device__ __forceinline__ void gl16(const float* g, float* l) {
    __builtin_amdgcn_global_load_lds(
        (__attribute__((address_space(1))) void*)(g),
        (__attribute__((address_space(3))) void*)(l), 16, 0, 0);
}

// ---------------- K0: alpha = sigmoid(mean_b inputs) ----------------
__global__ void k0_alpha(const float* __restrict__ inp, float* __restrict__ ws) {
    int n = threadIdx.x;
    if (n < NN) {
        float s = 0.f;
        for (int b = 0; b < NB; b++) s += inp[b * NN + n];
        s *= (1.0f / NB);
        ws[OFF_ALPHA + n] = 1.0f / (1.0f + expf(-s));
    }
}

// ---------------- K1: graph conv + layernorm -> hs ----------------
__global__ void k1_gcln(const float* __restrict__ inp, const float* __restrict__ hid,
                        const float* __restrict__ lap, const float* __restrict__ corr,
                        const float* __restrict__ gcw, const float* __restrict__ gcb,
                        const float* __restrict__ lng, const float* __restrict__ lnb,
                        float* __restrict__ ws) {
    int bm = blockIdx.x;
    int b = bm / NN, m = bm % NN;
    __shared__ float axs[33];
    __shared__ float hsh[32];
    const float* alpha = ws + OFF_ALPHA;
    int f = threadIdx.x;
    if (f < 33) {
        float s = 0.f;
        for (int n = 0; n < NN; n++) {
            float a = alpha[n];
            float A = a * lap[m * NN + n] + (1.0f - a) * corr[m * NN + n];
            float c = (f == 0) ? inp[b * NN + n] : hid[(b * NN + n) * 32 + (f - 1)];
            s += A * c;
        }
        axs[f] = s;
    }
    __syncthreads();
    int o = threadIdx.x;
    if (o < 32) {
        float h = gcb[o];
        for (int ff = 0; ff < 33; ff++) h += axs[ff] * gcw[ff * 32 + o];
        hsh[o] = h;
    }
    __syncthreads();
    if (o < 32) {
        float mu = 0.f;
        for (int j = 0; j < 32; j++) mu += hsh[j];
        mu *= (1.f / 32.f);
        float var = 0.f;
        for (int j = 0; j < 32; j++) { float d = hsh[j] - mu; var += d * d; }
        var *= (1.f / 32.f);
        float v = (hsh[o] - mu) / sqrtf(var + 1e-5f) * lng[o] + lnb[o];
        ws[OFF_HS + b * DF + m * 32 + o] = v;
    }
}

// ---------------- K2: gating scores -> gates[b][3] ----------------
__global__ void k2_gates(float* __restrict__ ws,
                         const float* __restrict__ minp, const float* __restrict__ maxp,
                         const float* __restrict__ mins, const float* __restrict__ maxs,
                         const float* __restrict__ minn, const float* __restrict__ maxn) {
    int b = blockIdx.x, t = threadIdx.x;
    const float* hs = ws + OFF_HS + (long)b * DF;
    __shared__ float c10[10], s10[10];
    __shared__ float red[12];
    if (t < 10) {
        float ang = 0.62831853071795864769f * (float)t;  // 2*pi/10 * t
        c10[t] = cosf(ang);
        s10[t] = sinf(ang);
    }
    __syncthreads();
    float psum = 0.f, ssum = 0.f, nsum = 0.f;
    const int NWIN = (DF - 10) / 2 + 1;  // 1596
    for (int w = t; w < NWIN; w += 256) {
        float x[10];
#pragma unroll
        for (int j = 0; j < 10; j++) x[j] = hs[w * 2 + j];
#pragma unroll
        for (int k = 0; k < 10; k++) {
            float re = 0.f, im = 0.f;
#pragma unroll
            for (int j = 0; j < 10; j++) {
                int m = (j * k) % 10;
                re += x[j] * c10[m];
                im += x[j] * s10[m];
            }
            psum += sqrtf(re * re + im * im);
        }
#pragma unroll
        for (int j = 0; j < 9; j++) ssum += fabsf(x[j + 1] - x[j]);
    }
    for (int d = t; d < DF - 2; d += 256)
        nsum += fabsf(hs[d + 2] - 2.0f * hs[d + 1] + hs[d]);
    // block reduce
    for (int off = 32; off > 0; off >>= 1) {
        psum += __shfl_down(psum, off, 64);
        ssum += __shfl_down(ssum, off, 64);
        nsum += __shfl_down(nsum, off, 64);
    }
    int lane = t & 63, wid = t >> 6;
    if (lane == 0) { red[wid] = psum; red[4 + wid] = ssum; red[8 + wid] = nsum; }
    __syncthreads();
    if (t == 0) {
        float pt = red[0] + red[1] + red[2] + red[3];
        float st = red[4] + red[5] + red[6] + red[7];
        float nt = red[8] + red[9] + red[10] + red[11];
        float pm = pt / (float)(NWIN * 10);
        float sm = st / (float)(NWIN * 9);
        float nm = nt / (float)(DF - 2);
        float p = fabsf((pm - *minp) / (*maxp - *minp + 1e-8f));
        float s = 1.0f - fabsf((sm - *mins) / (*maxs - *mins + 1e-8f));
        float n = fabsf((nm - *minn) / (*maxn - *minn + 1e-8f));
        float a0 = fabsf(p), a1 = fabsf(s), a2 = fabsf(n);
        float mx = fmaxf(a0, fmaxf(a1, a2));
        float e0 = expf(a0 - mx), e1 = expf(a1 - mx), e2 = expf(a2 - mx);
        float inv = 1.0f / (e0 + e1 + e2);
        ws[OFF_GATES + b * 4 + 0] = e0 * inv;
        ws[OFF_GATES + b * 4 + 1] = e1 * inv;
        ws[OFF_GATES + b * 4 + 2] = e2 * inv;
    }
}

// ---------------- K3: per-element expert features ----------------
__device__ __forceinline__ float gv(int j) { return 0.4f * (float)(j - 3) - 1.0f; }

__global__ void k3_feat(float* __restrict__ ws) {
    int q = blockIdx.x * 256 + threadIdx.x;  // 0..102399
    int i = q >> 5, b = q & 31;
    float x = ws[OFF_HS + (long)b * DF + i];
    float g0 = ws[OFF_GATES + b * 4 + 0];
    float g1 = ws[OFF_GATES + b * 4 + 1];
    float g2 = ws[OFF_GATES + b * 4 + 2];
    // Chebyshev: cos(d*arccos(tanh(xc))) == T_d(tanh(xc))
    float xc = g0 * x;
    float tt = tanhf(xc);
    float4 cb;
    cb.x = 1.0f;
    cb.y = tt;
    cb.z = 2.0f * tt * tt - 1.0f;
    cb.w = (4.0f * tt * tt - 3.0f) * tt;
    ((float4*)(ws + OFF_CB))[q] = cb;
    // Taylor powers
    float xt = g2 * x;
    float4 pw;
    pw.x = xt; pw.y = xt * xt; pw.z = xt * xt * xt; pw.w = 0.f;
    ((float4*)(ws + OFF_PW))[q] = pw;
    // SiLU
    float xb = g1 * x;
    ws[OFF_SILU + q] = xb / (1.0f + expf(-xb));
    // B-spline bases, Cox-de Boor degree 3 on uniform grid
    float prev[11], cur[11];
#pragma unroll
    for (int j = 0; j < 11; j++)
        prev[j] = (xb >= gv(j) && xb < gv(j + 1)) ? 1.0f : 0.0f;
#pragma unroll
    for (int d = 1; d <= 3; d++) {
#pragma unroll
        for (int j = 0; j + d < 11; j++) {
            float l = (xb - gv(j)) / (gv(j + d) - gv(j)) * prev[j];
            float r = (gv(j + d + 1) - xb) / (gv(j + d + 1) - gv(j + 1)) * prev[j + 1];
            cur[j] = l + r;
        }
#pragma unroll
        for (int j = 0; j + d < 11; j++) prev[j] = cur[j];
    }
    float4 s0, s1;
    s0.x = prev[0]; s0.y = prev[1]; s0.z = prev[2]; s0.w = prev[3];
    s1.x = prev[4]; s1.y = prev[5]; s1.z = prev[6]; s1.w = prev[7];
    ((float4*)(ws + OFF_SB))[q * 2 + 0] = s0;
    ((float4*)(ws + OFF_SB))[q * 2 + 1] = s1;
}

// ---------------- E1: Chebyshev + Taylor experts ([i][o][f] layout) ----------------
// P=2 outputs/thread, depth-2 register prefetch of the weight stream.
#define E1_IC 32
__global__ __launch_bounds__(256) void e1_cheb_taylor(
        const float* __restrict__ cheb, const float* __restrict__ tay,
        const float* __restrict__ ws, float* __restrict__ out) {
    int t = threadIdx.x;
    int o1 = blockIdx.x * 512 + t;
    int o2 = o1 + 256;
    bool v1 = o1 < DF, v2 = o2 < DF;
    int i0 = blockIdx.y * E1_IC;
    const float4* cb4 = (const float4*)(ws + OFF_CB);
    const float4* pw4 = (const float4*)(ws + OFF_PW);
    float acc1[32], acc2[32];
#pragma unroll
    for (int b = 0; b < 32; b++) { acc1[b] = 0.f; acc2[b] = 0.f; }

    float4 wAn[2], wBn[2];
    float tAn[2][3], tBn[2][3];
#pragma unroll
    for (int u = 0; u < 2; u++) {
        wAn[u] = make_float4(0.f, 0.f, 0.f, 0.f);
        wBn[u] = make_float4(0.f, 0.f, 0.f, 0.f);
        tAn[u][0] = tAn[u][1] = tAn[u][2] = 0.f;
        tBn[u][0] = tBn[u][1] = tBn[u][2] = 0.f;
    }
    // prefetch group 0
#pragma unroll
    for (int u = 0; u < 2; u++) {
        int i = i0 + u;
        if (v1) {
            wAn[u] = *(const float4*)(cheb + ((long)i * DF + o1) * 4);
            const float* tp = tay + ((long)i * DF + o1) * 3;
            tAn[u][0] = tp[0]; tAn[u][1] = tp[1]; tAn[u][2] = tp[2];
        }
        if (v2) {
            wBn[u] = *(const float4*)(cheb + ((long)i * DF + o2) * 4);
            const float* tp = tay + ((long)i * DF + o2) * 3;
            tBn[u][0] = tp[0]; tBn[u][1] = tp[1]; tBn[u][2] = tp[2];
        }
    }
    for (int ii = 0; ii < E1_IC; ii += 2) {
        float4 wA[2], wB[2];
        float tA[2][3], tB[2][3];
#pragma unroll
        for (int u = 0; u < 2; u++) {
            wA[u] = wAn[u]; wB[u] = wBn[u];
            tA[u][0] = tAn[u][0]; tA[u][1] = tAn[u][1]; tA[u][2] = tAn[u][2];
            tB[u][0] = tBn[u][0]; tB[u][1] = tBn[u][1]; tB[u][2] = tBn[u][2];
        }
        if (ii + 2 < E1_IC) {
#pragma unroll
            for (int u = 0; u < 2; u++) {
                int i = i0 + ii + 2 + u;
                if (v1) {
                    wAn[u] = *(const float4*)(cheb + ((long)i * DF + o1) * 4);
                    const float* tp = tay + ((long)i * DF + o1) * 3;
                    tAn[u][0] = tp[0]; tAn[u][1] = tp[1]; tAn[u][2] = tp[2];
                }
                if (v2) {
                    wBn[u] = *(const float4*)(cheb + ((long)i * DF + o2) * 4);
                    const float* tp = tay + ((long)i * DF + o2) * 3;
                    tBn[u][0] = tp[0]; tBn[u][1] = tp[1]; tBn[u][2] = tp[2];
                }
            }
        }
#pragma unroll
        for (int u = 0; u < 2; u++) {
            long i = i0 + ii + u;
            const float4* cp = cb4 + i * 32;
            const float4* pp = pw4 + i * 32;
#pragma unroll
            for (int b = 0; b < 32; b++) {
                float4 c = cp[b];
                float4 p = pp[b];
                acc1[b] += wA[u].x * c.x + wA[u].y * c.y + wA[u].z * c.z + wA[u].w * c.w
                         + tA[u][0] * p.x + tA[u][1] * p.y + tA[u][2] * p.z;
                acc2[b] += wB[u].x * c.x + wB[u].y * c.y + wB[u].z * c.z + wB[u].w * c.w
                         + tB[u][0] * p.x + tB[u][1] * p.y + tB[u][2] * p.z;
            }
        }
    }
    if (v1) {
#pragma unroll
        for (int b = 0; b < 32; b++) atomicAdd(out + (long)b * DF + o1, acc1[b]);
    }
    if (v2) {
#pragma unroll
        for (int b = 0; b < 32; b++) atomicAdd(out + (long)b * DF + o2, acc2[b]);
    }
}

// ---------------- E2: B-spline expert ----------------
// 8(o)x4(b) register tile per thread; weights+acts staged via global_load_lds,
// double-buffered; weight slots XOR-swizzled (p = q ^ ((q>>5)&7), involution).
#define E2_IC 40
#define E2_NC 20
__global__ __launch_bounds__(256) void e2_spline(
        const float* __restrict__ spw, const float* __restrict__ ws,
        float* __restrict__ out) {
    __shared__ __align__(16) float wbuf[2][4096];  // 256 cols x 16 floats (2i x 8k)
    __shared__ __align__(16) float abuf[2][512];   // [2i][32b][8k]
    int t = threadIdx.x;
    int og = t & 31, bg = t >> 5;
    int o0 = blockIdx.x * 256;
    int iblk = blockIdx.y * E2_IC;
    const float* sbf = ws + OFF_SB;
    float acc[8][4];
#pragma unroll
    for (int oo = 0; oo < 8; oo++)
#pragma unroll
        for (int c4 = 0; c4 < 4; c4++) acc[oo][c4] = 0.f;

    // stage chunk 0
    {
#pragma unroll
        for (int r = 0; r < 4; r++) {
            int p = r * 256 + t;
            int q = p ^ ((p >> 5) & 7);
            int col = q >> 2, j = q & 3;
            int oc = min(o0 + col, DF - 1);
            gl16(spw + ((long)oc * DF + iblk) * 8 + j * 4, &wbuf[0][p * 4]);
        }
        if (t < 128) gl16(sbf + (long)iblk * 256 + t * 4, &abuf[0][t * 4]);
    }
    __syncthreads();
    for (int c = 0; c < E2_NC; c++) {
        if (c + 1 < E2_NC) {
            int i0c = iblk + (c + 1) * 2;
            int nb = (c + 1) & 1;
#pragma unroll
            for (int r = 0; r < 4; r++) {
                int p = r * 256 + t;
                int q = p ^ ((p >> 5) & 7);
                int col = q >> 2, j = q & 3;
                int oc = min(o0 + col, DF - 1);
                gl16(spw + ((long)oc * DF + i0c) * 8 + j * 4, &wbuf[nb][p * 4]);
            }
            if (t < 128) gl16(sbf + (long)i0c * 256 + t * 4, &abuf[nb][t * 4]);
        }
        const float* wb = wbuf[c & 1];
        const float* ab = abuf[c & 1];
#pragma unroll
        for (int ii = 0; ii < 2; ii++) {
#pragma unroll
            for (int kq = 0; kq < 2; kq++) {
                float4 w[8];
#pragma unroll
                for (int oo = 0; oo < 8; oo++) {
                    int q = (og * 8 + oo) * 4 + ii * 2 + kq;  // q>>5 == og
                    int p = q ^ (og & 7);
                    w[oo] = *(const float4*)(wb + p * 4);
                }
                float4 a[4];
#pragma unroll
                for (int c4 = 0; c4 < 4; c4++)
                    a[c4] = *(const float4*)(ab + ii * 256 + (bg * 4 + c4) * 8 + kq * 4);
#pragma unroll
                for (int oo = 0; oo < 8; oo++)
#pragma unroll
                    for (int c4 = 0; c4 < 4; c4++)
                        acc[oo][c4] += w[oo].x * a[c4].x + w[oo].y * a[c4].y
                                     + w[oo].z * a[c4].z + w[oo].w * a[c4].w;
            }
        }
        __syncthreads();
    }
#pragma unroll
    for (int oo = 0; oo < 8; oo++) {
        int o = o0 + og * 8 + oo;
        if (o < DF) {
#pragma unroll
            for (int c4 = 0; c4 < 4; c4++)
                atomicAdd(out + (long)(bg * 4 + c4) * DF + o, acc[oo][c4]);
        }
    }
}

// ---------------- E3: SiLU base expert ([o][i] layout) ----------------
// thread=o; weights via global_load_lds dbuf (swizzle p = q ^ ((q>>3)&7));
// silu activations staged to LDS, read as broadcast float4 over b.
#define E3_IC 64
#define E3_NC 4
__global__ __launch_bounds__(256) void e3_base(
        const float* __restrict__ bw, const float* __restrict__ ws,
        float* __restrict__ out) {
    __shared__ __align__(16) float wbuf[2][4096];  // 256 cols x 16 floats (16 i)
    __shared__ __align__(16) float abuf[2][512];   // [16i][32b]
    int t = threadIdx.x;
    int o0 = blockIdx.x * 256;
    int o = o0 + t;
    bool valid = o < DF;
    int iblk = blockIdx.y * E3_IC;
    const float* slf = ws + OFF_SILU;
    float acc[32];
#pragma unroll
    for (int b = 0; b < 32; b++) acc[b] = 0.f;

    {
#pragma unroll
        for (int r = 0; r < 4; r++) {
            int p = r * 256 + t;
            int q = p ^ ((p >> 3) & 7);
            int col = q >> 2, j = q & 3;
            int oc = min(o0 + col, DF - 1);
            gl16(bw + (long)oc * DF + iblk + j * 4, &wbuf[0][p * 4]);
        }
        if (t < 128) gl16(slf + (long)iblk * 32 + t * 4, &abuf[0][t * 4]);
    }
    __syncthreads();
    for (int cc = 0; cc < E3_NC; cc++) {
        if (cc + 1 < E3_NC) {
            int i0c = iblk + (cc + 1) * 16;
            int nb = (cc + 1) & 1;
#pragma unroll
            for (int r = 0; r < 4; r++) {
                int p = r * 256 + t;
                int q = p ^ ((p >> 3) & 7);
                int col = q >> 2, j = q & 3;
                int oc = min(o0 + col, DF - 1);
                gl16(bw + (long)oc * DF + i0c + j * 4, &wbuf[nb][p * 4]);
            }
            if (t < 128) gl16(slf + (long)i0c * 32 + t * 4, &abuf[nb][t * 4]);
        }
        const float* wb = wbuf[cc & 1];
        const float* ab = abuf[cc & 1];
#pragma unroll
        for (int j = 0; j < 4; j++) {
            int q = t * 4 + j;                 // q>>3 == t>>1
            int p = q ^ ((t >> 1) & 7);
            float4 w = *(const float4*)(wb + p * 4);
            float wf[4] = {w.x, w.y, w.z, w.w};
#pragma unroll
            for (int c4 = 0; c4 < 4; c4++) {
                const float4* ap = (const float4*)(ab + (j * 4 + c4) * 32);
                float wv = wf[c4];
#pragma unroll
                for (int bgi = 0; bgi < 8; bgi++) {
                    float4 a = ap[bgi];
                    acc[bgi * 4 + 0] += wv * a.x;
                    acc[bgi * 4 + 1] += wv * a.y;
                    acc[bgi * 4 + 2] += wv * a.z;
                    acc[bgi * 4 + 3] += wv * a.w;
                }
            }
        }
        __syncthreads();
    }
    if (valid) {
#pragma unroll
        for (int b = 0; b < 32; b++) atomicAdd(out + (long)b * DF + o, acc[b]);
    }
}

extern "C" void kernel_launch(void* const* d_in, const int* in_sizes, int n_in,
                              void* d_out, int out_size, void* d_ws, size_t ws_size,
                              hipStream_t stream) {
    const float* inp  = (const float*)d_in[0];
    const float* hid  = (const float*)d_in[1];
    const float* lap  = (const float*)d_in[2];
    const float* corr = (const float*)d_in[3];
    const float* gcw  = (const float*)d_in[4];
    const float* gcb  = (const float*)d_in[5];
    const float* lng  = (const float*)d_in[6];
    const float* lnb  = (const float*)d_in[7];
    const float* cheb = (const float*)d_in[8];
    const float* bw   = (const float*)d_in[9];
    const float* spw  = (const float*)d_in[10];
    const float* tay  = (const float*)d_in[11];
    const float* minp = (const float*)d_in[12];
    const float* maxp = (const float*)d_in[13];
    const float* mins = (const float*)d_in[14];
    const float* maxs = (const float*)d_in[15];
    const float* minn = (const float*)d_in[16];
    const float* maxn = (const float*)d_in[17];
    float* out = (float*)d_out;
    float* ws  = (float*)d_ws;

    hipMemsetAsync(d_out, 0, (size_t)out_size * sizeof(float), stream);

    k0_alpha<<<1, 128, 0, stream>>>(inp, ws);
    k1_gcln<<<NB * NN, 64, 0, stream>>>(inp, hid, lap, corr, gcw, gcb, lng, lnb, ws);
    k2_gates<<<NB, 256, 0, stream>>>(ws, minp, maxp, mins, maxs, minn, maxn);
    k3_feat<<<(NB * DF) / 256, 256, 0, stream>>>(ws);

    e1_cheb_taylor<<<dim3(7, 100), 256, 0, stream>>>(cheb, tay, ws, out);
    e2_spline<<<dim3(13, 80), 256, 0, stream>>>(spw, ws, out);
    e3_base<<<dim3(13, 50), 256, 0, stream>>>(bw, ws, out);
}